// Round 5
// baseline (136.447 us; speedup 1.0000x reference)
//
#include <hip/hip_runtime.h>
#include <hip/hip_bf16.h>

typedef __attribute__((ext_vector_type(8))) short bf16x8;
typedef __attribute__((ext_vector_type(4))) float f32x4;

#define B    4
#define CIN  128
#define COUT 256
#define H    256
#define W    256
#define HW   (H * W)
#define ROWS 16          // output rows per block
#define PXW  64          // px strip width per block

__device__ __forceinline__ unsigned short f2bf(float f) {
  unsigned int u = __builtin_bit_cast(unsigned int, f);
  u += 0x7fff + ((u >> 16) & 1);
  return (unsigned short)(u >> 16);
}

__global__ void cvt_wpw(const float* __restrict__ w, unsigned short* __restrict__ o) {
  int i = blockIdx.x * 256 + threadIdx.x;
  if (i < COUT * CIN) o[i] = f2bf(w[i]);
}

// rolling-window row fragment: 8 px + left/right halo
struct Row { float L; f32x4 a; f32x4 b; float R; };

__device__ __forceinline__ float rget(const Row& r, int j) {
  return (j < 0) ? r.L : (j < 4) ? r.a[j & 3] : (j < 8) ? r.b[j & 3] : r.R;
}

__device__ __forceinline__ Row load_row(const float* xr, int px0, bool pL, bool pR) {
  Row r;
  r.a = *(const f32x4*)(xr + px0);
  r.b = *(const f32x4*)(xr + px0 + 4);
  r.L = pL ? xr[px0 - 1] : 0.f;
  r.R = pR ? xr[px0 + 8] : 0.f;
  return r;
}

__device__ __forceinline__ Row zero_row() {
  Row r; r.L = r.R = 0.f;
  r.a = (f32x4){0.f,0.f,0.f,0.f};
  r.b = (f32x4){0.f,0.f,0.f,0.f};
  return r;
}

// LDS y-row layout: La = pxl*256 + ci*2 bytes; swizzle XORs px low bits into
// the 16B-granule bits -> b128 GEMM reads granule-balanced, writes ~8-way (cheap).
__device__ __forceinline__ unsigned swz(unsigned La) {
  return La ^ (((La >> 8) & 7) << 4);
}

__device__ __forceinline__ void dw_row(char* __restrict__ buf, int c, int pxg,
    const Row& A0, const Row& B0, const Row& C0,
    const Row& A1, const Row& B1, const Row& C1,
    const float (&w0)[9], const float (&w1)[9]) {
#pragma unroll
  for (int j = 0; j < 8; ++j) {
    float a0 =
      rget(A0,j-1)*w0[0] + rget(A0,j)*w0[1] + rget(A0,j+1)*w0[2] +
      rget(B0,j-1)*w0[3] + rget(B0,j)*w0[4] + rget(B0,j+1)*w0[5] +
      rget(C0,j-1)*w0[6] + rget(C0,j)*w0[7] + rget(C0,j+1)*w0[8];
    float a1 =
      rget(A1,j-1)*w1[0] + rget(A1,j)*w1[1] + rget(A1,j+1)*w1[2] +
      rget(B1,j-1)*w1[3] + rget(B1,j)*w1[4] + rget(B1,j+1)*w1[5] +
      rget(C1,j-1)*w1[6] + rget(C1,j)*w1[7] + rget(C1,j+1)*w1[8];
    unsigned pk = (unsigned)f2bf(a0) | ((unsigned)f2bf(a1) << 16);
    unsigned La = (unsigned)(pxg * 8 + j) * 256 + (unsigned)c * 4;
    *(unsigned*)(buf + swz(La)) = pk;
  }
}

// ---------------------------------------------------------------------------
// Fused dw3x3 + pw GEMM, pipelined over 16 rows per block.
// Grid 256 = b(4) x hc(16) x strip(4); 512 threads (8 waves).
// dw: thread = 2ci x 8px, rolling 3-row register window (x fetched once).
// pw: wave tile 32co x 64px, MFMA 16x16x32, K=128 from LDS (dbuf per row).
// Pipeline per row: issue loads(h+2) -> GEMM(h) + stores -> dw(h+1) ->
//   lgkmcnt(0) + raw s_barrier (stores NEVER drained inside the loop).
// ---------------------------------------------------------------------------
__global__ __launch_bounds__(512, 2) void fused_kernel(
    const float* __restrict__ x, const float* __restrict__ wdw,
    const unsigned short* __restrict__ wb, float* __restrict__ out)
{
  int bid = blockIdx.x;
  int st = bid & 3;
  int hc = (bid >> 2) & 15;
  int b  = bid >> 6;
  int hBase = hc * ROWS;

  int t = threadIdx.x;
  int c   = t >> 3;                 // 0..63: ci-pair
  int pxg = t & 7;                  // 0..7: 8 px each
  int ci0 = c * 2;
  int px0 = st * PXW + pxg * 8;     // global px
  bool pL = px0 > 0, pR = px0 + 8 < W;

  __shared__ __align__(16) char yb[2][PXW * 256];   // 2 x 16 KB

  float w0[9], w1[9];
#pragma unroll
  for (int k = 0; k < 9; ++k) { w0[k] = wdw[ci0 * 9 + k]; w1[k] = wdw[ci0 * 9 + 9 + k]; }

  const float* xc0 = x + ((size_t)b * CIN + ci0) * HW;
  const float* xc1 = xc0 + HW;

  // GEMM thread ids
  int wave = t >> 6, l = t & 63;
  int l15 = l & 15, lg = l >> 4;
  int coBase = wave * 32;

  bf16x8 Af[2][4];
#pragma unroll
  for (int m = 0; m < 2; ++m)
#pragma unroll
    for (int kk = 0; kk < 4; ++kk)
      Af[m][kk] = *(const bf16x8*)(wb + (coBase + m * 16 + l15) * CIN + kk * 32 + lg * 8);

  // ---- prologue: window rows (hBase-1, hBase, hBase+1); dw row hBase ----
  Row A0 = (hBase > 0) ? load_row(xc0 + (size_t)(hBase - 1) * W, px0, pL, pR) : zero_row();
  Row A1 = (hBase > 0) ? load_row(xc1 + (size_t)(hBase - 1) * W, px0, pL, pR) : zero_row();
  Row B0 = load_row(xc0 + (size_t)hBase * W, px0, pL, pR);
  Row B1 = load_row(xc1 + (size_t)hBase * W, px0, pL, pR);
  Row C0 = load_row(xc0 + (size_t)(hBase + 1) * W, px0, pL, pR);   // hBase+1 <= 241
  Row C1 = load_row(xc1 + (size_t)(hBase + 1) * W, px0, pL, pR);

  dw_row(yb[0], c, pxg, A0, B0, C0, A1, B1, C1, w0, w1);
  asm volatile("s_waitcnt lgkmcnt(0)" ::: "memory");
  __builtin_amdgcn_s_barrier();

  float* obase = out + (size_t)b * COUT * HW + st * PXW;

#pragma unroll
  for (int r = 0; r < ROWS; ++r) {
    int h = hBase + r;

    // issue next-next x row loads (consumed after GEMM; compiler emits counted vmcnt)
    Row D0, D1;
    if (r < ROWS - 1) {
      bool ok = (h + 2) < H;        // wave-uniform
      D0 = ok ? load_row(xc0 + (size_t)(h + 2) * W, px0, pL, pR) : zero_row();
      D1 = ok ? load_row(xc1 + (size_t)(h + 2) * W, px0, pL, pR) : zero_row();
    }

    // ---- GEMM row h from yb[r&1] ----
    const char* buf = yb[r & 1];
    f32x4 acc[2][4];
#pragma unroll
    for (int m = 0; m < 2; ++m)
#pragma unroll
      for (int n = 0; n < 4; ++n) acc[m][n] = (f32x4){0.f,0.f,0.f,0.f};

#pragma unroll
    for (int n = 0; n < 4; ++n) {
      bf16x8 Bf[4];
#pragma unroll
      for (int kk = 0; kk < 4; ++kk) {
        unsigned La = (unsigned)(n * 16 + l15) * 256 + (unsigned)(kk * 32 + lg * 8) * 2;
        Bf[kk] = *(const bf16x8*)(buf + swz(La));
      }
#pragma unroll
      for (int m = 0; m < 2; ++m)
#pragma unroll
        for (int kk = 0; kk < 4; ++kk)
          acc[m][n] = __builtin_amdgcn_mfma_f32_16x16x32_bf16(Af[m][kk], Bf[kk], acc[m][n], 0, 0, 0);
    }

    float* ob = obase + (size_t)h * W;
#pragma unroll
    for (int m = 0; m < 2; ++m)
#pragma unroll
      for (int n = 0; n < 4; ++n)
#pragma unroll
        for (int rr = 0; rr < 4; ++rr)
          ob[(size_t)(coBase + m * 16 + lg * 4 + rr) * HW + n * 16 + l15] = acc[m][n][rr];

    // ---- dw row h+1 into yb[(r+1)&1]; barrier (lgkm only, stores in flight) ----
    if (r < ROWS - 1) {
      dw_row(yb[(r + 1) & 1], c, pxg, B0, C0, D0, B1, C1, D1, w0, w1);
      asm volatile("s_waitcnt lgkmcnt(0)" ::: "memory");
      __builtin_amdgcn_s_barrier();
      A0 = B0; B0 = C0; C0 = D0;
      A1 = B1; B1 = C1; C1 = D1;
    }
  }
}

extern "C" void kernel_launch(void* const* d_in, const int* in_sizes, int n_in,
                              void* d_out, int out_size, void* d_ws, size_t ws_size,
                              hipStream_t stream) {
  const float* x   = (const float*)d_in[0];
  const float* wdw = (const float*)d_in[1];
  const float* wpw = (const float*)d_in[2];
  float* out = (float*)d_out;

  unsigned short* wbb = (unsigned short*)d_ws;   // 64 KB bf16 pw weights

  cvt_wpw<<<(COUT * CIN + 255) / 256, 256, 0, stream>>>(wpw, wbb);
  fused_kernel<<<B * (H / ROWS) * (W / PXW), 512, 0, stream>>>(x, wdw, wbb, out);
}

// Round 7
// 122.083 us; speedup vs baseline: 1.1177x; 1.1177x over previous
//
#include <hip/hip_runtime.h>
#include <hip/hip_bf16.h>

typedef __attribute__((ext_vector_type(8))) short bf16x8;
typedef __attribute__((ext_vector_type(4))) float f32x4;

#define B    4
#define CIN  128
#define COUT 256
#define H    256
#define W    256
#define HW   (H * W)
#define ROWS 8           // output rows per block
#define PXW  32          // px strip per block

__device__ __forceinline__ unsigned short f2bf(float f) {
  unsigned int u = __builtin_bit_cast(unsigned int, f);
  u += 0x7fff + ((u >> 16) & 1);
  return (unsigned short)(u >> 16);
}

__global__ void cvt_wpw(const float* __restrict__ w, unsigned short* __restrict__ o) {
  int i = blockIdx.x * 256 + threadIdx.x;
  if (i < COUT * CIN) o[i] = f2bf(w[i]);
}

// rolling-window fragment: 4 px + halos
struct R4v { float L; f32x4 v; float R; };

__device__ __forceinline__ float rg(const R4v& r, int j) {
  return (j < 0) ? r.L : (j < 4) ? r.v[j & 3] : r.R;
}

__device__ __forceinline__ R4v lr(const float* xr, int px0, bool pL, bool pR) {
  R4v r;
  r.v = *(const f32x4*)(xr + px0);
  r.L = pL ? xr[px0 - 1] : 0.f;
  r.R = pR ? xr[px0 + 4] : 0.f;
  return r;
}

__device__ __forceinline__ R4v zr() {
  R4v r; r.L = r.R = 0.f; r.v = (f32x4){0.f,0.f,0.f,0.f}; return r;
}

// LDS y layout: La = row*8192 + pxl*256 + ci*2 (bytes).
// swizzle: XOR 16B-granule bits (4-6) with (pxl&7)^(pxl>>3):
//   dw u32 writes -> exactly 2 lanes/bank (free)
//   GEMM b128 reads -> exactly 8 lanes/granule-column (b128 floor)
__device__ __forceinline__ unsigned swz(unsigned La) {
  unsigned g = ((La >> 8) & 7) ^ ((La >> 11) & 3);
  return La ^ (g << 4);
}

// ---------------------------------------------------------------------------
// Fused dw3x3 + pw GEMM. Independent blocks, ONE barrier per block.
// Grid 1024 = xcd(8) x [hcl(4) x s(8) x b(4)]; hc = xcd*4+hcl -> each XCD
// owns 4 consecutive h-chunks: halo rows L2-shared across co-resident blocks.
// Block: 8 rows x 32px x 128ci. 512 thr (8 waves), 64 KB LDS, 2 blocks/CU.
// dw: thread = 2ci x 4px, rolling 3-row register window (+1 prefetch row).
// pw: 8 waves, wave tile 32co x 32px, MFMA 16x16x32, K=128 from LDS.
// ---------------------------------------------------------------------------
__global__ __launch_bounds__(512, 4) void fused_kernel(
    const float* __restrict__ x, const float* __restrict__ wdw,
    const unsigned short* __restrict__ wb, float* __restrict__ out)
{
  int bid = blockIdx.x;
  int xcd = bid & 7;
  int k   = bid >> 3;          // 0..127
  int hcl = k & 3;
  int s   = (k >> 2) & 7;      // 8 strips of 32 px
  int b   = k >> 5;            // 0..3
  int hc  = xcd * 4 + hcl;     // 0..31
  int hBase = hc * ROWS;

  int t = threadIdx.x;
  int c   = t >> 3;            // 0..63 : ci-pair
  int pxg = t & 7;             // 0..7  : 4 px each
  int ci0 = c * 2;
  int px0 = s * PXW + pxg * 4; // global px
  bool pL = px0 > 0, pR = px0 + 4 < W;

  __shared__ __align__(16) char yb[ROWS * PXW * 256];   // 64 KB

  float w0[9], w1[9];
#pragma unroll
  for (int q = 0; q < 9; ++q) { w0[q] = wdw[ci0 * 9 + q]; w1[q] = wdw[ci0 * 9 + 9 + q]; }

  const float* xc0 = x + ((size_t)b * CIN + ci0) * HW;
  const float* xc1 = xc0 + HW;

  // ---- dw phase: rolling window, 8 rows, no internal barriers ----
  R4v A0 = (hBase > 0) ? lr(xc0 + (size_t)(hBase - 1) * W, px0, pL, pR) : zr();
  R4v A1 = (hBase > 0) ? lr(xc1 + (size_t)(hBase - 1) * W, px0, pL, pR) : zr();
  R4v B0 = lr(xc0 + (size_t)hBase * W, px0, pL, pR);
  R4v B1 = lr(xc1 + (size_t)hBase * W, px0, pL, pR);
  R4v C0 = lr(xc0 + (size_t)(hBase + 1) * W, px0, pL, pR);   // hBase+1 <= 249
  R4v C1 = lr(xc1 + (size_t)(hBase + 1) * W, px0, pL, pR);

#pragma unroll
  for (int r = 0; r < ROWS; ++r) {
    R4v D0, D1;
    if (r < ROWS - 1) {
      int hh = hBase + r + 2;
      bool ok = hh < H;                       // wave-uniform only at hc=31
      D0 = ok ? lr(xc0 + (size_t)hh * W, px0, pL, pR) : zr();
      D1 = ok ? lr(xc1 + (size_t)hh * W, px0, pL, pR) : zr();
    }

#pragma unroll
    for (int j = 0; j < 4; ++j) {
      float a0 =
        rg(A0,j-1)*w0[0] + rg(A0,j)*w0[1] + rg(A0,j+1)*w0[2] +
        rg(B0,j-1)*w0[3] + rg(B0,j)*w0[4] + rg(B0,j+1)*w0[5] +
        rg(C0,j-1)*w0[6] + rg(C0,j)*w0[7] + rg(C0,j+1)*w0[8];
      float a1 =
        rg(A1,j-1)*w1[0] + rg(A1,j)*w1[1] + rg(A1,j+1)*w1[2] +
        rg(B1,j-1)*w1[3] + rg(B1,j)*w1[4] + rg(B1,j+1)*w1[5] +
        rg(C1,j-1)*w1[6] + rg(C1,j)*w1[7] + rg(C1,j+1)*w1[8];
      unsigned pk = (unsigned)f2bf(a0) | ((unsigned)f2bf(a1) << 16);
      unsigned La = (unsigned)r * 8192 + (unsigned)(pxg * 4 + j) * 256 + (unsigned)c * 4;
      *(unsigned*)(yb + swz(La)) = pk;
    }

    if (r < ROWS - 1) {
      A0 = B0; B0 = C0; C0 = D0;
      A1 = B1; B1 = C1; C1 = D1;
    }
  }

  // ---- GEMM phase ----
  int wave = t >> 6, l = t & 63;
  int l15 = l & 15, lg = l >> 4;
  int coBase = wave * 32;

  bf16x8 Af[2][4];
#pragma unroll
  for (int m = 0; m < 2; ++m)
#pragma unroll
    for (int kk = 0; kk < 4; ++kk)
      Af[m][kk] = *(const bf16x8*)(wb + (coBase + m * 16 + l15) * CIN + kk * 32 + lg * 8);

  __syncthreads();

  float* obase = out + (size_t)b * COUT * HW + s * PXW;

#pragma unroll
  for (int r = 0; r < ROWS; ++r) {
    f32x4 acc[2][2];
#pragma unroll
    for (int m = 0; m < 2; ++m)
#pragma unroll
      for (int n = 0; n < 2; ++n) acc[m][n] = (f32x4){0.f,0.f,0.f,0.f};

#pragma unroll
    for (int n = 0; n < 2; ++n) {
      bf16x8 Bf[4];
#pragma unroll
      for (int kk = 0; kk < 4; ++kk) {
        unsigned La = (unsigned)r * 8192 + (unsigned)(n * 16 + l15) * 256
                    + (unsigned)(kk * 32 + lg * 8) * 2;
        Bf[kk] = *(const bf16x8*)(yb + swz(La));
      }
#pragma unroll
      for (int m = 0; m < 2; ++m)
#pragma unroll
        for (int kk = 0; kk < 4; ++kk)
          acc[m][n] = __builtin_amdgcn_mfma_f32_16x16x32_bf16(Af[m][kk], Bf[kk], acc[m][n], 0, 0, 0);
    }

    float* ob = obase + (size_t)(hBase + r) * W;
#pragma unroll
    for (int m = 0; m < 2; ++m)
#pragma unroll
      for (int n = 0; n < 2; ++n)
#pragma unroll
        for (int rr = 0; rr < 4; ++rr)
          ob[(size_t)(coBase + m * 16 + lg * 4 + rr) * HW + n * 16 + l15] = acc[m][n][rr];
  }
}

extern "C" void kernel_launch(void* const* d_in, const int* in_sizes, int n_in,
                              void* d_out, int out_size, void* d_ws, size_t ws_size,
                              hipStream_t stream) {
  const float* x   = (const float*)d_in[0];
  const float* wdw = (const float*)d_in[1];
  const float* wpw = (const float*)d_in[2];
  float* out = (float*)d_out;

  unsigned short* wbb = (unsigned short*)d_ws;   // 64 KB bf16 pw weights

  cvt_wpw<<<(COUT * CIN + 255) / 256, 256, 0, stream>>>(wpw, wbb);
  fused_kernel<<<B * (H / ROWS) * (W / PXW), 512, 0, stream>>>(x, wdw, wbb, out);
}

// Round 8
// 104.989 us; speedup vs baseline: 1.2996x; 1.1628x over previous
//
#include <hip/hip_runtime.h>
#include <hip/hip_bf16.h>

typedef __attribute__((ext_vector_type(8))) short bf16x8;
typedef __attribute__((ext_vector_type(4))) float f32x4;

#define B    4
#define CIN  128
#define COUT 256
#define H    256
#define W    256
#define HW   (H * W)
#define ROWS 8           // output rows per block
#define PXW  64          // px strip per block

__device__ __forceinline__ unsigned short f2bf(float f) {
  unsigned int u = __builtin_bit_cast(unsigned int, f);
  u += 0x7fff + ((u >> 16) & 1);
  return (unsigned short)(u >> 16);
}

__global__ void cvt_wpw(const float* __restrict__ w, unsigned short* __restrict__ o) {
  int i = blockIdx.x * 256 + threadIdx.x;
  if (i < COUT * CIN) o[i] = f2bf(w[i]);
}

// rolling-window fragment: 8 px + halos
struct Row { float L; f32x4 a; f32x4 b; float R; };

__device__ __forceinline__ float rget(const Row& r, int j) {
  return (j < 0) ? r.L : (j < 4) ? r.a[j & 3] : (j < 8) ? r.b[j & 3] : r.R;
}

__device__ __forceinline__ Row load_row(const float* xr, int px0, bool pL, bool pR) {
  Row r;
  r.a = *(const f32x4*)(xr + px0);
  r.b = *(const f32x4*)(xr + px0 + 4);
  r.L = pL ? xr[px0 - 1] : 0.f;
  r.R = pR ? xr[px0 + 8] : 0.f;
  return r;
}

__device__ __forceinline__ Row zero_row() {
  Row r; r.L = r.R = 0.f;
  r.a = (f32x4){0.f,0.f,0.f,0.f};
  r.b = (f32x4){0.f,0.f,0.f,0.f};
  return r;
}

// LDS y layout: La = r*16384 + pxl*256 + ci*2 (bytes); 8x64x128 bf16 = 128 KB.
// swizzle: XOR granule bits 4-6 with (pxl&7)^(pxl>>3):
//   dw u16 writes: granule = w ^ j ^ pxg -> 8 granules, 2 lanes/bank (free)
//   GEMM b128 reads: 8 lanes/granule = the b128 floor (1KB/instr in 8 batches)
__device__ __forceinline__ unsigned swz(unsigned La) {
  unsigned g = ((La >> 8) & 7) ^ ((La >> 11) & 7);
  return La ^ (g << 4);
}

// ---------------------------------------------------------------------------
// Fused dw3x3 + pw GEMM. Block = 8 rows x 64 px x ALL 128 ci; 1024 thr
// (16 waves), 128 KB LDS, 1 block/CU, ONE barrier per block.
// Halo amp by construction: (10/8 rows) x (384/256 px bytes) = 1.875.
// dw: thread = 1 ci x 8 px, rolling 3-row register window (+1 prefetch row).
// pw: 16 waves, wave tile 16co x 64px, MFMA 16x16x32, K=128 from LDS,
//     acc reset + store per row (no cross-row liveness).
// Grid 512 = xcd(8) x [hcl(4) x s(4) x b(4)]; hc = xcd*4+hcl -> each XCD owns
// a contiguous h-band; strip/row neighbors co-resident on same XCD for L2.
// ---------------------------------------------------------------------------
__global__ __launch_bounds__(1024, 4) void fused_kernel(
    const float* __restrict__ x, const float* __restrict__ wdw,
    const unsigned short* __restrict__ wb, float* __restrict__ out)
{
  int bid = blockIdx.x;
  int xcd = bid & 7;
  int k   = bid >> 3;          // 0..63
  int hcl = k & 3;
  int s   = (k >> 2) & 3;      // 4 strips of 64 px
  int b   = k >> 4;            // 0..3
  int hc  = xcd * 4 + hcl;     // 0..31
  int hBase = hc * ROWS;

  int t = threadIdx.x;
  int ci  = t >> 3;            // 0..127
  int pxg = t & 7;             // 0..7, 8 px each
  int px0 = s * PXW + pxg * 8; // global px
  bool pL = px0 > 0, pR = px0 + 8 < W;

  __shared__ __align__(16) char yb[ROWS * PXW * CIN * 2];   // 128 KB

  float wr[9];
#pragma unroll
  for (int q = 0; q < 9; ++q) wr[q] = wdw[ci * 9 + q];

  const float* xc = x + ((size_t)b * CIN + ci) * HW;

  // ---- dw phase: rolling window over 10 rows, no internal barriers ----
  Row A  = (hBase > 0) ? load_row(xc + (size_t)(hBase - 1) * W, px0, pL, pR) : zero_row();
  Row Bv = load_row(xc + (size_t)hBase * W, px0, pL, pR);
  Row C  = load_row(xc + (size_t)(hBase + 1) * W, px0, pL, pR);   // hBase+1 <= 249

#pragma unroll
  for (int r = 0; r < ROWS; ++r) {
    Row D;
    if (r < ROWS - 1) {
      int hh = hBase + r + 2;
      bool ok = hh < H;                     // wave-uniform (only hc=31 tail)
      D = ok ? load_row(xc + (size_t)hh * W, px0, pL, pR) : zero_row();
    }

#pragma unroll
    for (int j = 0; j < 8; ++j) {
      float a =
        rget(A, j-1)*wr[0] + rget(A, j)*wr[1] + rget(A, j+1)*wr[2] +
        rget(Bv,j-1)*wr[3] + rget(Bv,j)*wr[4] + rget(Bv,j+1)*wr[5] +
        rget(C, j-1)*wr[6] + rget(C, j)*wr[7] + rget(C, j+1)*wr[8];
      unsigned La = (unsigned)r * 16384u + (unsigned)(pxg * 8 + j) * 256u + (unsigned)ci * 2u;
      *(unsigned short*)(yb + swz(La)) = f2bf(a);
    }

    if (r < ROWS - 1) { A = Bv; Bv = C; C = D; }
  }

  // ---- GEMM phase ----
  int wave = t >> 6, l = t & 63;
  int l15 = l & 15, lg = l >> 4;
  int coBase = wave * 16;      // 16 waves x 16 co = 256

  bf16x8 Af[4];                // issued before barrier to hide L2 latency
#pragma unroll
  for (int kk = 0; kk < 4; ++kk)
    Af[kk] = *(const bf16x8*)(wb + (coBase + l15) * CIN + kk * 32 + lg * 8);

  __syncthreads();

  float* ob = out + (size_t)b * COUT * HW + s * PXW;

#pragma unroll
  for (int r = 0; r < ROWS; ++r) {
    f32x4 acc[4];
#pragma unroll
    for (int n = 0; n < 4; ++n) acc[n] = (f32x4){0.f,0.f,0.f,0.f};

#pragma unroll
    for (int n = 0; n < 4; ++n) {
      bf16x8 Bf[4];
#pragma unroll
      for (int kk = 0; kk < 4; ++kk) {
        unsigned La = (unsigned)r * 16384u + (unsigned)(n * 16 + l15) * 256u
                    + (unsigned)(kk * 32 + lg * 8) * 2u;
        Bf[kk] = *(const bf16x8*)(yb + swz(La));
      }
#pragma unroll
      for (int kk = 0; kk < 4; ++kk)
        acc[n] = __builtin_amdgcn_mfma_f32_16x16x32_bf16(Af[kk], Bf[kk], acc[n], 0, 0, 0);
    }

    float* orow = ob + (size_t)(hBase + r) * W;
#pragma unroll
    for (int n = 0; n < 4; ++n)
#pragma unroll
      for (int rr = 0; rr < 4; ++rr)
        orow[(size_t)(coBase + lg * 4 + rr) * HW + n * 16 + l15] = acc[n][rr];
  }
}

extern "C" void kernel_launch(void* const* d_in, const int* in_sizes, int n_in,
                              void* d_out, int out_size, void* d_ws, size_t ws_size,
                              hipStream_t stream) {
  const float* x   = (const float*)d_in[0];
  const float* wdw = (const float*)d_in[1];
  const float* wpw = (const float*)d_in[2];
  float* out = (float*)d_out;

  unsigned short* wbb = (unsigned short*)d_ws;   // 64 KB bf16 pw weights

  cvt_wpw<<<(COUT * CIN + 255) / 256, 256, 0, stream>>>(wpw, wbb);
  fused_kernel<<<B * (H / ROWS) * (W / PXW), 1024, 0, stream>>>(x, wdw, wbb, out);
}